// Round 9
// baseline (347.611 us; speedup 1.0000x reference)
//
#include <hip/hip_runtime.h>

#define D_DIM 8192
#define SPLITK 4
#define KS 2048               // K per slice
#define BK 128
#define NITER 16              // KS/BK
#define NGROUP 320            // 32-row groups (q:0-255, k:256-287, v:288-319)

#define PART_BYTES (SPLITK * NGROUP * 1024 * 4)   // 5,242,880
#define XF_BYTES   (256 * 2 * 64 * 8 * 2)         // 524,288
#define WS_NEED    (PART_BYTES + XF_BYTES + NGROUP * 4)

typedef float f32x4 __attribute__((ext_vector_type(4)));
typedef short s16x8 __attribute__((ext_vector_type(8)));

static __device__ __forceinline__ unsigned short f2bf(float f) {
  union { float f; unsigned u; } v; v.f = f;
  return (unsigned short)((v.u + 0x7FFFu + ((v.u >> 16) & 1u)) >> 16);
}

// Precompute X fragments in per-lane MFMA A-operand order:
// xf[kstep][wm][lane][8] bf16, kstep = 0..255 over full D.
__global__ __launch_bounds__(256) void xprep(const float* __restrict__ x,
                                             unsigned short* __restrict__ xf) {
  const int cell = blockIdx.x * 256 + threadIdx.x;   // 32768 cells
  const int lane = cell & 63;
  const int wm   = (cell >> 6) & 1;
  const int kst  = cell >> 7;
  const float* s = x + (size_t)(wm * 16 + (lane & 15)) * D_DIM
                     + kst * 32 + (lane >> 4) * 8;
  f32x4 lo = *(const f32x4*)s;
  f32x4 hi = *(const f32x4*)(s + 4);
  s16x8 v;
  v[0]=(short)f2bf(lo[0]); v[1]=(short)f2bf(lo[1]);
  v[2]=(short)f2bf(lo[2]); v[3]=(short)f2bf(lo[3]);
  v[4]=(short)f2bf(hi[0]); v[5]=(short)f2bf(hi[1]);
  v[6]=(short)f2bf(hi[2]); v[7]=(short)f2bf(hi[3]);
  *(s16x8*)&xf[(size_t)cell * 8] = v;
}

// W stage: 16 consecutive floats per thread (thread t -> row t>>3, cols (t&7)*16..+16)
#define WLOAD(ST, CH) do {                                                      \
    const float* wp_ = wrow + kbase + (size_t)(CH) * BK;                        \
    ST[0] = *(const f32x4*)(wp_ + 0);  ST[1] = *(const f32x4*)(wp_ + 4);        \
    ST[2] = *(const f32x4*)(wp_ + 8);  ST[3] = *(const f32x4*)(wp_ + 12);       \
  } while (0)

// fp32 -> bf16, two b128 writes into XOR-swizzled (8-col-granular) LDS buffer
#define CVT_WRITE(ST, BUF) do {                                                 \
    s16x8 v0_, v1_;                                                             \
    v0_[0]=(short)f2bf(ST[0][0]); v0_[1]=(short)f2bf(ST[0][1]);                 \
    v0_[2]=(short)f2bf(ST[0][2]); v0_[3]=(short)f2bf(ST[0][3]);                 \
    v0_[4]=(short)f2bf(ST[1][0]); v0_[5]=(short)f2bf(ST[1][1]);                 \
    v0_[6]=(short)f2bf(ST[1][2]); v0_[7]=(short)f2bf(ST[1][3]);                 \
    v1_[0]=(short)f2bf(ST[2][0]); v1_[1]=(short)f2bf(ST[2][1]);                 \
    v1_[2]=(short)f2bf(ST[2][2]); v1_[3]=(short)f2bf(ST[2][3]);                 \
    v1_[4]=(short)f2bf(ST[3][0]); v1_[5]=(short)f2bf(ST[3][1]);                 \
    v1_[6]=(short)f2bf(ST[3][2]); v1_[7]=(short)f2bf(ST[3][3]);                 \
    *(s16x8*)&ldsw[BUF][wrl * BK + wc0s] = v0_;                                 \
    *(s16x8*)&ldsw[BUF][wrl * BK + wc1s] = v1_;                                 \
  } while (0)

// 4 k-steps: A from precomputed xf (16B coalesced, L2-hot, k-slice based!),
// B from LDS (swizzled)
#define COMPUTE(BUF, C) do {                                                    \
    _Pragma("unroll")                                                           \
    for (int s_ = 0; s_ < 4; ++s_) {                                            \
      s16x8 fa_ = *(const s16x8*)&xfp[(size_t)(((C)*4 + s_)*2 + wm) * 512 + lane * 8]; \
      s16x8 fb_ = *(const s16x8*)&ldsw[BUF][brow * BK + (((s_*4 + kq) ^ (brow & 7)) * 8)]; \
      acc = __builtin_amdgcn_mfma_f32_16x16x32_bf16(fa_, fb_, acc, 0, 0, 0);    \
    } } while (0)

__global__ __launch_bounds__(256, 5) void qkv_gemm(
    const float* __restrict__ wq, const float* __restrict__ wk,
    const float* __restrict__ wv, const unsigned short* __restrict__ xf,
    float* __restrict__ wsb, int* __restrict__ cnt, float* __restrict__ out)
{
  // W-only double buffer: [2][32*128] bf16 = 16 KiB
  __shared__ unsigned short ldsw[2][32 * BK];
  __shared__ int slast;

  // XCD-bijective remap: each XCD gets one k-slice (x-frag L2 reuse x160)
  const int xcd   = blockIdx.x & 7;
  const int j     = blockIdx.x >> 3;          // 0..159
  const int ksl   = xcd >> 1;
  const int group = (xcd & 1) * 160 + j;      // 0..319
  const int n0    = group * 32;

  const float* wptr; int erow0, outbase;
  if (n0 < 8192)      { wptr = wq; outbase = 0;      erow0 = n0; }
  else if (n0 < 9216) { wptr = wk; outbase = 262144; erow0 = n0 - 8192; }
  else                { wptr = wv; outbase = 294912; erow0 = n0 - 9216; }

  const int tid  = threadIdx.x;
  const int lane = tid & 63;
  const int w    = tid >> 6;
  const size_t kbase = (size_t)ksl * KS;

  // xf base for THIS k-slice: 64 k-steps per slice (R8 bug: this was missing)
  const unsigned short* xfp = xf + (size_t)(ksl * 64 * 2) * 512;

  // staging geometry
  const float* wrow = wptr + (size_t)(erow0 + (tid >> 3)) * D_DIM + (tid & 7) * 16;
  const int wrl  = tid >> 3;                   // LDS row
  const int g0   = (tid & 7) * 2;              // 8-col group index
  const int wc0s = ((g0     ^ (wrl & 7)) * 8);
  const int wc1s = (((g0+1) ^ (wrl & 7)) * 8);

  // MFMA fragment addressing
  const int wm   = w >> 1, wn = w & 1;
  const int la   = lane & 15;
  const int kq   = lane >> 4;
  const int brow = wn * 16 + la;

  f32x4 acc = {0.f, 0.f, 0.f, 0.f};
  f32x4 wst0[4], wst1[4];

  WLOAD(wst0, 0);
  WLOAD(wst1, 1);
  CVT_WRITE(wst0, 0);

  #pragma unroll
  for (int c = 0; c < NITER; c += 2) {
    __syncthreads();                      // buf0 (chunk c) ready; buf1 free
    COMPUTE(0, c);
    if (c + 2 < NITER) WLOAD(wst0, c + 2);
    CVT_WRITE(wst1, 1);                   // chunk c+1
    __syncthreads();                      // buf1 ready; buf0 free
    COMPUTE(1, c + 1);
    if (c + 3 < NITER) WLOAD(wst1, c + 3);
    if (c + 2 < NITER) CVT_WRITE(wst0, 0);  // chunk c+2
  }

  // partial: ws[ksl][group][b*32+n]  (C/D: col=lane&15=n, row=kq*4+r=batch)
  const int m0 = kq * 4;
  float* p = wsb + ((size_t)(ksl * NGROUP + group)) * 1024;
  #pragma unroll
  for (int r = 0; r < 4; ++r)
    p[(wm * 16 + m0 + r) * 32 + wn * 16 + la] = acc[r];

  __threadfence();                        // release partials (device scope)
  if (tid == 0) slast = atomicAdd(&cnt[group], 1);
  __syncthreads();
  if (slast == SPLITK - 1) {              // last k-slice block: fused reduce
    __threadfence();                      // acquire other blocks' partials
    const int idx = tid * 4;              // b*32 + n, 4 consecutive n
    f32x4 s = {0.f, 0.f, 0.f, 0.f};
    #pragma unroll
    for (int sl = 0; sl < SPLITK; ++sl) {
      f32x4 v = *(const f32x4*)(wsb + ((size_t)(sl * NGROUP + group)) * 1024 + idx);
      s[0] += v[0]; s[1] += v[1]; s[2] += v[2]; s[3] += v[3];
    }
    const int b  = idx >> 5;
    const int n  = idx & 31;
    const int er = erow0 + n;
    *(f32x4*)(out + outbase + (er >> 7) * 4096 + b * 128 + (er & 127)) = s;
  }
}

extern "C" void kernel_launch(void* const* d_in, const int* in_sizes, int n_in,
                              void* d_out, int out_size, void* d_ws, size_t ws_size,
                              hipStream_t stream) {
  const float* x  = (const float*)d_in[0];
  const float* wq = (const float*)d_in[1];
  const float* wk = (const float*)d_in[2];
  const float* wv = (const float*)d_in[3];
  float* out = (float*)d_out;

  float*          part = (float*)d_ws;
  unsigned short* xf   = (unsigned short*)((char*)d_ws + PART_BYTES);
  int*            cnt  = (int*)((char*)d_ws + PART_BYTES + XF_BYTES);

  hipMemsetAsync(cnt, 0, NGROUP * sizeof(int), stream);
  xprep<<<dim3(128), dim3(256), 0, stream>>>(x, xf);
  qkv_gemm<<<dim3(NGROUP * SPLITK), dim3(256), 0, stream>>>(
      wq, wk, wv, xf, part, cnt, out);
}